// Round 12
// baseline (183.128 us; speedup 1.0000x reference)
//
#include <hip/hip_runtime.h>

#define SEQ   2048
#define BATCH 4
#define DIM   512
#define VA    65536
#define PA    131072
#define LDS_TOTAL 132096
#define NEG_INF  (-__builtin_inff())

typedef short short8 __attribute__((ext_vector_type(8)));
typedef float floatx4 __attribute__((ext_vector_type(4)));

using lds_char = __attribute__((address_space(3))) char;
using g_void   = const __attribute__((address_space(1))) void;
using l_void   = __attribute__((address_space(3))) void;

__device__ __forceinline__ short to_bf16(float x){
    unsigned u = __float_as_uint(x);
    unsigned r = (u + 0x7fffu + ((u >> 16) & 1u)) >> 16;
    return (short)r;
}

__device__ __forceinline__ short8 pack8(floatx4 a, floatx4 b, float s){
    short8 r;
    r[0]=to_bf16(a[0]*s); r[1]=to_bf16(a[1]*s); r[2]=to_bf16(a[2]*s); r[3]=to_bf16(a[3]*s);
    r[4]=to_bf16(b[0]*s); r[5]=to_bf16(b[1]*s); r[6]=to_bf16(b[2]*s); r[7]=to_bf16(b[3]*s);
    return r;
}

// K [k][b][d] fp32 -> Kimg [b][k][d] bf16, per-row 16B-slot XOR swizzle baked in.
extern "C" __global__ void __launch_bounds__(256)
conv_k(const float* __restrict__ K, short* __restrict__ Kimg)
{
    const int t    = blockIdx.x * 256 + threadIdx.x;   // 524288
    const int d8   = t & 63;
    const int row  = t >> 6;                           // k*BATCH + b
    const int k    = row >> 2;
    const int b    = row & 3;
    const float* src = K + (size_t)row * DIM + d8 * 8;
    floatx4 f0 = *(const floatx4*)src;
    floatx4 f1 = *(const floatx4*)(src + 4);
    const int slot = (d8 * 8) ^ ((k & 7) << 3);        // shorts
    *(short8*)(Kimg + ((size_t)b * SEQ + k) * DIM + slot) = pack8(f0, f1, 1.0f);
}

// V [k][b][dv] fp32 -> Vt [b][dv][k] bf16 (transposed, LINEAR — proven).
extern "C" __global__ void __launch_bounds__(256)
conv_v(const float* __restrict__ V, short* __restrict__ Vt)
{
    const int t    = blockIdx.x * 256 + threadIdx.x;   // 524288
    const int dv   = t & 511;
    const int rest = t >> 9;
    const int kc   = rest & 255;
    const int b    = rest >> 8;
    short8 colv;
    #pragma unroll
    for (int i = 0; i < 8; ++i){
        const float f = V[((size_t)(kc*8 + i) * BATCH + b) * DIM + dv];
        colv[i] = to_bf16(f);
    }
    *(short8*)(Vt + ((size_t)b * DIM + dv) * SEQ + kc * 8) = colv;
}

extern "C" __global__ void __launch_bounds__(256, 1)
fa_fwd(const float* __restrict__ Qg, const short* __restrict__ Kb,
       const short* __restrict__ Vt, const unsigned char* __restrict__ Mg,
       float* __restrict__ Og)
{
    extern __shared__ __align__(16) char smem[];
    const int tid  = threadIdx.x;
    const int w    = tid >> 6;        // 0..3 : dv quarter for PV + DMA piece
    const int lane = tid & 63;
    const int g    = lane >> 4;
    const int c    = lane & 15;

    // XCD pinning: batch fixed per XCD pair.
    const int slot = blockIdx.x & 7;
    const int b    = slot >> 1;
    const int qh   = slot & 1;
    const int s    = blockIdx.x >> 3;            // 0..31

    const short* Kbb = Kb + (size_t)b * SEQ * DIM;
    const short* Vtb = Vt + (size_t)b * DIM * SEQ;

    // wave w stages one 16KB piece of the (K,K,V,V) pair for 32-kv-row group ti
    // into double-buffer dd. K pieces: rows ti*32 + j*16 .. +16 (swizzled image,
    // linear copy). V pieces: [dv=512][k=16] rows for k-chunk j (linear copy).
    #define STAGE(ti, dd) { \
        if (w < 2){ \
            const short* ksrc_ = Kbb + ((size_t)((ti)*32 + w*16)) * DIM + lane*8; \
            char* dst_ = smem + (dd)*32768 + w*16384; \
            _Pragma("unroll") \
            for (int i_ = 0; i_ < 16; ++i_) \
                __builtin_amdgcn_global_load_lds((g_void*)(ksrc_ + (size_t)i_*DIM), \
                    (l_void*)(lds_char*)(dst_ + i_*1024), 16, 0, 0); \
        } else { \
            const int j_ = w - 2; \
            char* dst_ = smem + VA + (dd)*32768 + j_*16384; \
            _Pragma("unroll") \
            for (int i_ = 0; i_ < 16; ++i_){ \
                const short* vsrc_ = Vtb + (size_t)(i_*32 + (lane>>1))*SEQ \
                                   + (ti)*32 + j_*16 + (lane&1)*8; \
                __builtin_amdgcn_global_load_lds((g_void*)vsrc_, \
                    (l_void*)(lds_char*)(dst_ + i_*1024), 16, 0, 0); } \
        } }

    const float scale = 0.04419417382415922f;  // 1/sqrt(512)
    short8 qreg[16];
    floatx4 oacc[8];
    float mrow[4], lrow[4];

    STAGE(0, 0);   // prologue for phase 0, iter 0

    #pragma unroll 1
    for (int phase = 0; phase < 2; ++phase){
        const int qt    = phase ? (63 - s) : s;
        const int qrow0 = qt*32 + qh*16;
        const int iters = qt + 1;

        {   // Q -> registers (16 rows, bf16, pre-scaled)
            const float* qrow = Qg + ((size_t)(qrow0 + c) * BATCH + b) * DIM + g * 8;
            #pragma unroll
            for (int ks = 0; ks < 16; ++ks){
                floatx4 f0 = *(const floatx4*)(qrow + ks*32);
                floatx4 f1 = *(const floatx4*)(qrow + ks*32 + 4);
                qreg[ks] = pack8(f0, f1, scale);
            }
        }
        #pragma unroll
        for (int i=0;i<8;++i){ floatx4 z = {0.f,0.f,0.f,0.f}; oacc[i]=z; }
        #pragma unroll
        for (int jj=0;jj<4;++jj){ mrow[jj] = NEG_INF; lrow[jj] = 0.f; }

        #pragma unroll 1
        for (int i = 0; i < iters; ++i){
            const int d  = i & 1;
            const int kb = i * 32;

            asm volatile("s_waitcnt vmcnt(0)" ::: "memory");
            __syncthreads();   // [A] K(i),V(i) landed; prior reads of buf d done

            if (i + 1 < iters) STAGE(i + 1, d ^ 1);

            const char* kb_ = smem + d*32768;
            const char* vb_ = smem + VA + d*32768;

            const unsigned char km0 = Mg[(kb + c) * BATCH + b];
            const unsigned char km1 = Mg[(kb + 16 + c) * BATCH + b];

            // ---- S = Q K^T : 2 16-col tiles (redundant across waves) ----
            floatx4 sacc[2];
            { floatx4 z = {0.f,0.f,0.f,0.f}; sacc[0]=z; sacc[1]=z; }
            #pragma unroll
            for (int ks = 0; ks < 16; ++ks){
                #pragma unroll
                for (int j = 0; j < 2; ++j){
                    short8 kf = *(const short8*)(kb_ + j*16384 + c*1024 +
                                   ((ks*64 + g*16) ^ ((c & 7) << 4)));
                    sacc[j] = __builtin_amdgcn_mfma_f32_16x16x32_bf16(qreg[ks], kf, sacc[j], 0,0,0);
                }
            }

            // ---- mask + online softmax ----
            float sv[2][4];
            #pragma unroll
            for (int j = 0; j < 2; ++j){
                const int col = kb + j*16 + c;
                const unsigned char km = j ? km1 : km0;
                #pragma unroll
                for (int jj = 0; jj < 4; ++jj){
                    const int row = qrow0 + g*4 + jj;
                    sv[j][jj] = (col > row || km) ? NEG_INF : sacc[j][jj];
                }
            }
            float pmax[4];
            #pragma unroll
            for (int jj=0;jj<4;++jj) pmax[jj] = fmaxf(sv[0][jj], sv[1][jj]);
            #pragma unroll
            for (int msk=1; msk<16; msk<<=1){
                #pragma unroll
                for (int jj=0;jj<4;++jj)
                    pmax[jj] = fmaxf(pmax[jj], __shfl_xor(pmax[jj], msk, 64));
            }
            const bool okd = (pmax[0] <= mrow[0]+8.f) && (pmax[1] <= mrow[1]+8.f)
                          && (pmax[2] <= mrow[2]+8.f) && (pmax[3] <= mrow[3]+8.f);
            if (!__all(okd)){
                float fsc[4];
                #pragma unroll
                for (int jj=0;jj<4;++jj){
                    const float M = fmaxf(mrow[jj], pmax[jj]);
                    const float f = (mrow[jj] == NEG_INF) ? 0.f : __expf(mrow[jj] - M);
                    mrow[jj] = M; lrow[jj] *= f; fsc[jj] = f;
                }
                #pragma unroll
                for (int nt=0; nt<8; ++nt){
                    #pragma unroll
                    for (int jj=0; jj<4; ++jj) oacc[nt][jj] *= fsc[jj];
                }
            }
            float parr[2][4], psum[4] = {0.f,0.f,0.f,0.f};
            #pragma unroll
            for (int j=0; j<2; ++j){
                #pragma unroll
                for (int jj=0; jj<4; ++jj){
                    const float x = sv[j][jj];
                    const float e = (x == NEG_INF) ? 0.f : __expf(x - mrow[jj]);
                    parr[j][jj] = e; psum[jj] += e;
                }
            }
            #pragma unroll
            for (int msk=1; msk<16; msk<<=1){
                #pragma unroll
                for (int jj=0;jj<4;++jj) psum[jj] += __shfl_xor(psum[jj], msk, 64);
            }
            #pragma unroll
            for (int jj=0;jj<4;++jj) lrow[jj] += psum[jj];

            // ---- P [16q][32k]: all waves write identical bytes (benign) ----
            #pragma unroll
            for (int j=0; j<2; ++j){
                #pragma unroll
                for (int jj=0; jj<4; ++jj)
                    *(short*)(smem + PA + (g*4 + jj)*64 + (j*16 + c)*2) = to_bf16(parr[j][jj]);
            }

            // ---- O += P V on this wave's dv quarter (8 tiles, k=32 each) ----
            const short8 pfrag = *(const short8*)(smem + PA + c*64 + g*16);
            #pragma unroll
            for (int nt = 0; nt < 8; ++nt){
                const int dv = w*128 + nt*16 + c;
                const short8 vfr = *(const short8*)(vb_ + (g>>1)*16384 + dv*32 + (g&1)*16);
                oacc[nt] = __builtin_amdgcn_mfma_f32_16x16x32_bf16(pfrag, vfr, oacc[nt], 0,0,0);
            }
        }

        __syncthreads();   // all reads of both buffers done
        if (phase == 0) STAGE(0, 0);   // prefetch phase-1 iter 0 under O-write

        // ---- write O for this phase (wave owns dv quarter) ----
        #pragma unroll
        for (int jj=0; jj<4; ++jj){
            const float inv = (lrow[jj] > 0.f) ? 1.0f / lrow[jj] : 0.f;
            float* orow = Og + ((size_t)(qrow0 + g*4 + jj) * BATCH + b) * DIM + w*128 + c;
            #pragma unroll
            for (int nt=0; nt<8; ++nt) orow[nt*16] = oacc[nt][jj] * inv;
        }
    }
    #undef STAGE
}

extern "C" void kernel_launch(void* const* d_in, const int* in_sizes, int n_in,
                              void* d_out, int out_size, void* d_ws, size_t ws_size,
                              hipStream_t stream)
{
    const float* Q = (const float*)d_in[0];
    const float* K = (const float*)d_in[1];
    const float* V = (const float*)d_in[2];
    const unsigned char* M = (const unsigned char*)d_in[3];
    float* O = (float*)d_out;
    (void)in_sizes; (void)n_in; (void)out_size; (void)ws_size;

    short* Kb = (short*)d_ws;                               // 8 MB swizzled K image
    short* Vt = Kb + (size_t)BATCH * SEQ * DIM;             // 8 MB linear V^T image

    conv_k<<<2048, 256, 0, stream>>>(K, Kb);
    conv_v<<<2048, 256, 0, stream>>>(V, Vt);

    hipFuncSetAttribute(reinterpret_cast<const void*>(fa_fwd),
                        hipFuncAttributeMaxDynamicSharedMemorySize, LDS_TOTAL);
    fa_fwd<<<256, 256, LDS_TOTAL, stream>>>(Q, Kb, Vt, M, O);
}

// Round 13
// 138.597 us; speedup vs baseline: 1.3213x; 1.3213x over previous
//
#include <hip/hip_runtime.h>

#define SEQ   2048
#define BATCH 4
#define DIM   512
#define VAOFF 65536
#define PAOFF 131072
#define LDS_TOTAL 139264
#define NEG_INF  (-__builtin_inff())

typedef short short8 __attribute__((ext_vector_type(8)));
typedef float floatx4 __attribute__((ext_vector_type(4)));

using lds_char = __attribute__((address_space(3))) char;
using g_void   = const __attribute__((address_space(1))) void;
using l_void   = __attribute__((address_space(3))) void;

__device__ __forceinline__ short to_bf16(float x){
    unsigned u = __float_as_uint(x);
    unsigned r = (u + 0x7fffu + ((u >> 16) & 1u)) >> 16;
    return (short)r;
}

__device__ __forceinline__ short8 pack8(floatx4 a, floatx4 b, float s){
    short8 r;
    r[0]=to_bf16(a[0]*s); r[1]=to_bf16(a[1]*s); r[2]=to_bf16(a[2]*s); r[3]=to_bf16(a[3]*s);
    r[4]=to_bf16(b[0]*s); r[5]=to_bf16(b[1]*s); r[6]=to_bf16(b[2]*s); r[7]=to_bf16(b[7-7]*s);
    return r;
}

// NOTE: pack8 above must use b[3] in last slot; fixed below via explicit code.
__device__ __forceinline__ short8 pack8f(floatx4 a, floatx4 b, float s){
    short8 r;
    r[0]=to_bf16(a[0]*s); r[1]=to_bf16(a[1]*s); r[2]=to_bf16(a[2]*s); r[3]=to_bf16(a[3]*s);
    r[4]=to_bf16(b[0]*s); r[5]=to_bf16(b[1]*s); r[6]=to_bf16(b[2]*s); r[7]=to_bf16(b[3]*s);
    return r;
}

// K [k][b][d] fp32 -> Kimg [b][k][d] bf16, per-row 16B-slot XOR swizzle baked in.
extern "C" __global__ void __launch_bounds__(256)
conv_k(const float* __restrict__ K, short* __restrict__ Kimg)
{
    const int t    = blockIdx.x * 256 + threadIdx.x;   // 524288
    const int d8   = t & 63;
    const int row  = t >> 6;                           // k*BATCH + b
    const int k    = row >> 2;
    const int b    = row & 3;
    const float* src = K + (size_t)row * DIM + d8 * 8;
    floatx4 f0 = *(const floatx4*)src;
    floatx4 f1 = *(const floatx4*)(src + 4);
    const int slot = (d8 * 8) ^ ((k & 7) << 3);        // shorts
    *(short8*)(Kimg + ((size_t)b * SEQ + k) * DIM + slot) = pack8f(f0, f1, 1.0f);
}

// V [k][b][dv] fp32 -> Vt [b][dv][k] bf16 (transposed, LINEAR — proven).
extern "C" __global__ void __launch_bounds__(256)
conv_v(const float* __restrict__ V, short* __restrict__ Vt)
{
    const int t    = blockIdx.x * 256 + threadIdx.x;   // 524288
    const int dv   = t & 511;
    const int rest = t >> 9;
    const int kc   = rest & 255;
    const int b    = rest >> 8;
    short8 colv;
    #pragma unroll
    for (int i = 0; i < 8; ++i){
        const float f = V[((size_t)(kc*8 + i) * BATCH + b) * DIM + dv];
        colv[i] = to_bf16(f);
    }
    *(short8*)(Vt + ((size_t)b * DIM + dv) * SEQ + kc * 8) = colv;
}

// Combine the two kv-parity partials -> final O.  partO fp32 [inst][32][512].
extern "C" __global__ void __launch_bounds__(256)
merge_o(const float* __restrict__ partO, const float* __restrict__ stats,
        float* __restrict__ Og)
{
    const int t = blockIdx.x * 256 + threadIdx.x;      // 4,194,304
    const int d = t & 511;
    const int u = t >> 9;
    const int b = u & 3;
    const int v = u >> 2;                              // global q row 0..2047
    const int qt = v >> 5;
    const int r  = v & 31;
    const int p0 = (qt*4 + b)*2;
    const float O0 = partO[((size_t)p0*32 + r)*512 + d];
    const float O1 = partO[((size_t)(p0+1)*32 + r)*512 + d];
    const float m0 = stats[p0*64 + r],     l0 = stats[p0*64 + 32 + r];
    const float m1 = stats[(p0+1)*64 + r], l1 = stats[(p0+1)*64 + 32 + r];
    const float M  = fmaxf(m0, m1);
    const float a0 = (m0 == NEG_INF) ? 0.f : __expf(m0 - M);
    const float a1 = (m1 == NEG_INF) ? 0.f : __expf(m1 - M);
    const float l  = a0*l0 + a1*l1;
    const float inv = (l > 0.f) ? 1.0f/l : 0.f;
    Og[((size_t)v*BATCH + b)*DIM + d] = (a0*O0 + a1*O1) * inv;
}

extern "C" __global__ void __launch_bounds__(512, 1)
fa_fwd(const float* __restrict__ Qg, const short* __restrict__ Kb,
       const short* __restrict__ Vt, const unsigned char* __restrict__ Mg,
       float* __restrict__ partO, float* __restrict__ stats)
{
    extern __shared__ __align__(16) char smem[];
    const int tid  = threadIdx.x;
    const int w    = tid >> 6;        // 0..7
    const int lane = tid & 63;
    const int g    = lane >> 4;
    const int c    = lane & 15;
    const int qhalf = w & 1;
    const int dvq   = w >> 1;         // dv quarter 0..3

    // XCD pinning: batch per XCD pair; h = kv parity; s = pair index.
    const int slot = blockIdx.x & 7;
    const int b    = slot >> 1;
    const int h    = slot & 1;
    const int s    = blockIdx.x >> 3;            // 0..31

    const int cntA  = (s + 2 - h) >> 1;          // qt=s, tiles t=h,h+2,.. < s+1
    const int cntB  = (65 - s - h) >> 1;         // qt=63-s
    const int total = cntA + cntB;               // 32 or 33, uniform

    const short* Kbb = Kb + (size_t)b * SEQ * DIM;
    const short* Vtb = Vt + (size_t)b * DIM * SEQ;

    char* Pb = smem + PAOFF + w*1024;

    // wave-role staging: w<4 stage K rows [w*8,w*8+8); w>=4 stage a V piece.
    #define STAGE(tt, dd) { \
        if (w < 4){ \
            const short* ksrc_ = Kbb + ((size_t)((tt)*32 + w*8)) * DIM + lane*8; \
            char* dst_ = smem + (dd)*32768 + w*8192; \
            _Pragma("unroll") \
            for (int i2 = 0; i2 < 8; ++i2) \
                __builtin_amdgcn_global_load_lds((g_void*)(ksrc_ + (size_t)i2*DIM), \
                    (l_void*)(lds_char*)(dst_ + i2*1024), 16, 0, 0); \
        } else { \
            const int u_ = w - 4, j_ = u_ >> 1, hi_ = u_ & 1; \
            char* dst_ = smem + VAOFF + (dd)*32768 + j_*16384 + hi_*8192; \
            _Pragma("unroll") \
            for (int i2 = 0; i2 < 8; ++i2){ \
                const int iv_ = hi_*8 + i2; \
                const short* vsrc_ = Vtb + (size_t)(iv_*32 + (lane>>1))*SEQ \
                                   + (tt)*32 + j_*16 + (lane&1)*8; \
                __builtin_amdgcn_global_load_lds((g_void*)vsrc_, \
                    (l_void*)(lds_char*)(dst_ + i2*1024), 16, 0, 0); } \
        } }

    #define TILE_OF(j) ((j) < cntA ? (h + 2*(j)) : (h + 2*((j) - cntA)))

    const float scale = 0.04419417382415922f;  // 1/sqrt(512)
    short8 qreg[16];
    floatx4 oacc[8];
    float mrow[4], lrow[4];
    int qt_cur = s;

    // ---- load Q for phase A, reset state ----
    {
        const float* qrow = Qg + ((size_t)(s*32 + qhalf*16 + c) * BATCH + b) * DIM + g * 8;
        #pragma unroll
        for (int ks = 0; ks < 16; ++ks){
            floatx4 f0 = *(const floatx4*)(qrow + ks*32);
            floatx4 f1 = *(const floatx4*)(qrow + ks*32 + 4);
            qreg[ks] = pack8f(f0, f1, scale);
        }
    }
    #pragma unroll
    for (int i=0;i<8;++i){ floatx4 z = {0.f,0.f,0.f,0.f}; oacc[i]=z; }
    #pragma unroll
    for (int jj=0;jj<4;++jj){ mrow[jj] = NEG_INF; lrow[jj] = 0.f; }

    STAGE(TILE_OF(0), 0);

    #pragma unroll 1
    for (int j = 0; j < total; ++j){

        if (j == cntA){
            // ---- finalize phase A: write partial + stats, switch to B ----
            const int inst = (s*4 + b)*2 + h;
            float* po = partO + (size_t)inst * 32 * 512;
            #pragma unroll
            for (int nt = 0; nt < 8; ++nt){
                #pragma unroll
                for (int jj = 0; jj < 4; ++jj)
                    po[(size_t)(qhalf*16 + g*4 + jj)*512 + dvq*128 + nt*16 + c] = oacc[nt][jj];
            }
            if (dvq == 0 && c == 0){
                #pragma unroll
                for (int jj = 0; jj < 4; ++jj){
                    const int R = qhalf*16 + g*4 + jj;
                    stats[inst*64 + R]      = mrow[jj];
                    stats[inst*64 + 32 + R] = lrow[jj];
                }
            }
            qt_cur = 63 - s;
            const float* qrow = Qg + ((size_t)(qt_cur*32 + qhalf*16 + c) * BATCH + b) * DIM + g * 8;
            #pragma unroll
            for (int ks = 0; ks < 16; ++ks){
                floatx4 f0 = *(const floatx4*)(qrow + ks*32);
                floatx4 f1 = *(const floatx4*)(qrow + ks*32 + 4);
                qreg[ks] = pack8f(f0, f1, scale);
            }
            #pragma unroll
            for (int i=0;i<8;++i){ floatx4 z = {0.f,0.f,0.f,0.f}; oacc[i]=z; }
            #pragma unroll
            for (int jj=0;jj<4;++jj){ mrow[jj] = NEG_INF; lrow[jj] = 0.f; }
        }

        const int d  = j & 1;
        const int kb = TILE_OF(j) * 32;
        const int qrow0 = qt_cur*32 + qhalf*16;

        asm volatile("s_waitcnt vmcnt(0)" ::: "memory");
        __syncthreads();   // [A] K(j),V(j) landed; prior reads of buf d done

        if (j + 1 < total) STAGE(TILE_OF(j+1), d ^ 1);

        const char* kb_ = smem + d*32768;
        const char* vb_ = smem + VAOFF + d*32768;

        const unsigned char km0 = Mg[(kb + c) * BATCH + b];
        const unsigned char km1 = Mg[(kb + 16 + c) * BATCH + b];

        // ---- S = Q K^T (redundant across dvq) ----
        floatx4 sacc[2];
        { floatx4 z = {0.f,0.f,0.f,0.f}; sacc[0]=z; sacc[1]=z; }
        #pragma unroll
        for (int ks = 0; ks < 16; ++ks){
            #pragma unroll
            for (int jcol = 0; jcol < 2; ++jcol){
                short8 kf = *(const short8*)(kb_ + jcol*16384 + c*1024 +
                               ((ks*64 + g*16) ^ ((c & 7) << 4)));
                sacc[jcol] = __builtin_amdgcn_mfma_f32_16x16x32_bf16(qreg[ks], kf, sacc[jcol], 0,0,0);
            }
        }

        // ---- mask + online softmax ----
        float sv[2][4];
        #pragma unroll
        for (int jcol = 0; jcol < 2; ++jcol){
            const int col = kb + jcol*16 + c;
            const unsigned char km = jcol ? km1 : km0;
            #pragma unroll
            for (int jj = 0; jj < 4; ++jj){
                const int row = qrow0 + g*4 + jj;
                sv[jcol][jj] = (col > row || km) ? NEG_INF : sacc[jcol][jj];
            }
        }
        float pmax[4];
        #pragma unroll
        for (int jj=0;jj<4;++jj) pmax[jj] = fmaxf(sv[0][jj], sv[1][jj]);
        #pragma unroll
        for (int msk=1; msk<16; msk<<=1){
            #pragma unroll
            for (int jj=0;jj<4;++jj)
                pmax[jj] = fmaxf(pmax[jj], __shfl_xor(pmax[jj], msk, 64));
        }
        const bool okd = (pmax[0] <= mrow[0]+8.f) && (pmax[1] <= mrow[1]+8.f)
                      && (pmax[2] <= mrow[2]+8.f) && (pmax[3] <= mrow[3]+8.f);
        if (!__all(okd)){
            float fsc[4];
            #pragma unroll
            for (int jj=0;jj<4;++jj){
                const float M = fmaxf(mrow[jj], pmax[jj]);
                const float f = (mrow[jj] == NEG_INF) ? 0.f : __expf(mrow[jj] - M);
                mrow[jj] = M; lrow[jj] *= f; fsc[jj] = f;
            }
            #pragma unroll
            for (int nt=0; nt<8; ++nt){
                #pragma unroll
                for (int jj=0; jj<4; ++jj) oacc[nt][jj] *= fsc[jj];
            }
        }
        float parr[2][4], psum[4] = {0.f,0.f,0.f,0.f};
        #pragma unroll
        for (int jcol=0; jcol<2; ++jcol){
            #pragma unroll
            for (int jj=0; jj<4; ++jj){
                const float x = sv[jcol][jj];
                const float e = (x == NEG_INF) ? 0.f : __expf(x - mrow[jj]);
                parr[jcol][jj] = e; psum[jj] += e;
            }
        }
        #pragma unroll
        for (int msk=1; msk<16; msk<<=1){
            #pragma unroll
            for (int jj=0;jj<4;++jj) psum[jj] += __shfl_xor(psum[jj], msk, 64);
        }
        #pragma unroll
        for (int jj=0;jj<4;++jj) lrow[jj] += psum[jj];

        // ---- P [16q][32k] per-wave ----
        #pragma unroll
        for (int jcol=0; jcol<2; ++jcol){
            #pragma unroll
            for (int jj=0; jj<4; ++jj)
                *(short*)(Pb + (g*4 + jj)*64 + (jcol*16 + c)*2) = to_bf16(parr[jcol][jj]);
        }

        // ---- O += P V on this wave's dv quarter ----
        const short8 pfrag = *(const short8*)(Pb + c*64 + g*16);
        #pragma unroll
        for (int nt = 0; nt < 8; ++nt){
            const int dv = dvq*128 + nt*16 + c;
            const short8 vfr = *(const short8*)(vb_ + (g>>1)*16384 + dv*32 + (g&1)*16);
            oacc[nt] = __builtin_amdgcn_mfma_f32_16x16x32_bf16(pfrag, vfr, oacc[nt], 0,0,0);
        }
    }

    // ---- finalize phase B ----
    {
        const int inst = ((63 - s)*4 + b)*2 + h;
        float* po = partO + (size_t)inst * 32 * 512;
        #pragma unroll
        for (int nt = 0; nt < 8; ++nt){
            #pragma unroll
            for (int jj = 0; jj < 4; ++jj)
                po[(size_t)(qhalf*16 + g*4 + jj)*512 + dvq*128 + nt*16 + c] = oacc[nt][jj];
        }
        if (dvq == 0 && c == 0){
            #pragma unroll
            for (int jj = 0; jj < 4; ++jj){
                const int R = qhalf*16 + g*4 + jj;
                stats[inst*64 + R]      = mrow[jj];
                stats[inst*64 + 32 + R] = lrow[jj];
            }
        }
    }
    #undef STAGE
    #undef TILE_OF
}

extern "C" void kernel_launch(void* const* d_in, const int* in_sizes, int n_in,
                              void* d_out, int out_size, void* d_ws, size_t ws_size,
                              hipStream_t stream)
{
    const float* Q = (const float*)d_in[0];
    const float* K = (const float*)d_in[1];
    const float* V = (const float*)d_in[2];
    const unsigned char* M = (const unsigned char*)d_in[3];
    float* O = (float*)d_out;
    (void)in_sizes; (void)n_in; (void)out_size; (void)ws_size;

    short* Kb    = (short*)d_ws;                              // 8.4 MB swizzled K image
    short* Vt    = Kb + (size_t)BATCH * SEQ * DIM;            // 8.4 MB linear V^T image
    float* partO = (float*)(Vt + (size_t)BATCH * SEQ * DIM);  // 33.6 MB fp32 partials
    float* stats = partO + (size_t)512 * 32 * 512;            // 128 KB m/l

    conv_k<<<2048, 256, 0, stream>>>(K, Kb);
    conv_v<<<2048, 256, 0, stream>>>(V, Vt);

    hipFuncSetAttribute(reinterpret_cast<const void*>(fa_fwd),
                        hipFuncAttributeMaxDynamicSharedMemorySize, LDS_TOTAL);
    fa_fwd<<<256, 512, LDS_TOTAL, stream>>>(Q, Kb, Vt, M, partO, stats);

    merge_o<<<16384, 256, 0, stream>>>(partO, stats, O);
}